// Round 4
// baseline (1585.101 us; speedup 1.0000x reference)
//
#include <hip/hip_runtime.h>

// ---------------------------------------------------------------------------
// MPN (chemprop) on MI355X. bf16 MFMA (16x16x32), fp32 accum.
//   relu(inp + m@W_h) == relu([f_bonds | m] @ [W_i ; W_h])  -> no stored inp.
// R1: 1-D grid, XCD-paired decode (n-half pairs 8 dispatch slots apart).
// R2: de-fused combine — REVERTED (gather belongs fused; GEMM wasn't
//     staging-bound).
// R3: depth-2 LDS pipeline + counted barrier — only +8%; MfmaUtil stuck ~15%.
//     Diagnosis: 192 arch regs -> 2 waves/SIMD, 54 LDS b128 ops vs 20 MFMA
//     per block-kt, 4-wave barrier lockstep. The LDS staging structure IS the
//     bottleneck.
// R4: LDS-FREE, BARRIER-FREE GEMM. A and B fragments are loaded directly
//     from global memory in MFMA register layout (lane: row=tile+l16,
//     k=quad*8 -> one aligned 64B line per 4 lanes; all row strides are
//     multiples of 64B). Wt (300KB) stays L2-hot; fbp/gathered rows get
//     line reuse via L1/L2. Depth-2 register prefetch, pure imm-offset
//     addressing, no syncthreads anywhere. Combine re-fused via LINEARITY:
//     (amsg - msg) @ Wh = amsg@Wh + (-msg)@Wh, msg fragment sign-flipped by
//     XOR 0x80008000 (kills the bfsub VALU chain and one bf16 rounding).
// GEMM: block tile 128M x 160N (virtual), wave tile 64x80 (4x5), grid with
//     XCD-paired decode unchanged.
// Workspace (~367 MiB): wih | wto | fbp | amsg | msgA | msgB
// ---------------------------------------------------------------------------

#define DEVFN static __device__ __forceinline__

typedef __attribute__((ext_vector_type(8))) __bf16 bf16x8;
typedef __attribute__((ext_vector_type(4))) float floatx4;

DEVFN unsigned short f2bf(float f) {
    unsigned int u = __float_as_uint(f);
    u += 0x7FFFu + ((u >> 16) & 1u);   // RNE
    return (unsigned short)(u >> 16);
}
DEVFN float bf2f(unsigned int u) { return __uint_as_float(u << 16); }

// negate 8 packed bf16 (sign-bit XOR)
DEVFN uint4 negbf8(uint4 a) {
    return make_uint4(a.x ^ 0x80008000u, a.y ^ 0x80008000u,
                      a.z ^ 0x80008000u, a.w ^ 0x80008000u);
}

// ---------------------------------------------------------------------------
__global__ __launch_bounds__(256) void dbg_fill(float* out, int n, float v) {
    int t = blockIdx.x * 256 + threadIdx.x;
    if (t < n) out[t] = v;
}

// Wih[320][480]: k<147 -> W_i[k][n]; 160<=k<460 -> W_h[k-160][n]; else 0
__global__ __launch_bounds__(256) void prep_wih(const float* __restrict__ Wi,
                                                const float* __restrict__ Wh,
                                                unsigned short* __restrict__ Wt) {
    int t = blockIdx.x * 256 + threadIdx.x;
    if (t >= 320 * 480) return;
    int n = t / 480, k = t - n * 480;
    float v = 0.f;
    if (n < 300) {
        if (k < 147) v = Wi[k * 300 + n];
        else if (k >= 160 && k < 460) v = Wh[(k - 160) * 300 + n];
    }
    Wt[t] = f2bf(v);
}

// Wto[320][448]: k<300 -> W_o[133+k][n]; 304<=k<437 -> W_o[k-304][n]; else 0
__global__ __launch_bounds__(256) void prep_wto(const float* __restrict__ Wo,
                                                unsigned short* __restrict__ Wt) {
    int t = blockIdx.x * 256 + threadIdx.x;
    if (t >= 320 * 448) return;
    int n = t / 448, k = t - n * 448;
    float v = 0.f;
    if (n < 300) {
        if (k < 300) v = Wo[(133 + k) * 300 + n];
        else if (k >= 304 && k < 437) v = Wo[(k - 304) * 300 + n];
    }
    Wt[t] = f2bf(v);
}

// f_bonds [200000][147] fp32 -> [200000][160] bf16 padded
__global__ __launch_bounds__(256) void pad_bonds(const float* __restrict__ fb,
                                                 unsigned short* __restrict__ out) {
    int t = blockIdx.x * 256 + threadIdx.x;
    if (t >= 200000 * 20) return;
    int b = t / 20, c = t - b * 20;
    unsigned int o[4];
#pragma unroll
    for (int p = 0; p < 4; ++p) {
        int sc = c * 8 + p * 2;
        float v0 = (sc < 147) ? fb[(size_t)b * 147 + sc] : 0.f;
        float v1 = (sc + 1 < 147) ? fb[(size_t)b * 147 + sc + 1] : 0.f;
        o[p] = (unsigned int)f2bf(v0) | ((unsigned int)f2bf(v1) << 16);
    }
    *(uint4*)(out + (size_t)b * 160 + c * 8) = make_uint4(o[0], o[1], o[2], o[3]);
}

// f_atoms [100000][133] fp32 -> concat cols 304..447
__global__ __launch_bounds__(256) void atoms_concat(const float* __restrict__ fa,
                                                    unsigned short* __restrict__ concat) {
    int t = blockIdx.x * 256 + threadIdx.x;
    if (t >= 100000 * 18) return;
    int a = t / 18, c = t - a * 18;
    unsigned int o[4];
#pragma unroll
    for (int p = 0; p < 4; ++p) {
        int sc = c * 8 + p * 2;
        float v0 = (sc < 133) ? fa[(size_t)a * 133 + sc] : 0.f;
        float v1 = (sc + 1 < 133) ? fa[(size_t)a * 133 + sc + 1] : 0.f;
        o[p] = (unsigned int)f2bf(v0) | ((unsigned int)f2bf(v1) << 16);
    }
    *(uint4*)(concat + (size_t)a * 448 + 304 + c * 8) = make_uint4(o[0], o[1], o[2], o[3]);
}

// a_msg[a] = sum_j msg[a2b[a][j]]
template <int CH>
__global__ __launch_bounds__(256) void gather_sum(const unsigned short* __restrict__ msg,
                                                  const int* __restrict__ a2b,
                                                  unsigned short* __restrict__ out,
                                                  int ostride, int nA) {
    int t = blockIdx.x * 256 + threadIdx.x;
    if (t >= nA * CH) return;
    int a = t / CH, c = t - a * CH;
    float s[8] = {0, 0, 0, 0, 0, 0, 0, 0};
#pragma unroll
    for (int j = 0; j < 6; ++j) {
        int b = a2b[a * 6 + j];
        uint4 v = *(const uint4*)(msg + (size_t)b * 320 + c * 8);
        s[0] += bf2f(v.x & 0xffffu); s[1] += bf2f(v.x >> 16);
        s[2] += bf2f(v.y & 0xffffu); s[3] += bf2f(v.y >> 16);
        s[4] += bf2f(v.z & 0xffffu); s[5] += bf2f(v.z >> 16);
        s[6] += bf2f(v.w & 0xffffu); s[7] += bf2f(v.w >> 16);
    }
    unsigned int o[4];
#pragma unroll
    for (int p = 0; p < 4; ++p)
        o[p] = (unsigned int)f2bf(s[2 * p]) | ((unsigned int)f2bf(s[2 * p + 1]) << 16);
    *(uint4*)(out + (size_t)a * ostride + c * 8) = make_uint4(o[0], o[1], o[2], o[3]);
}

// ---------------------------------------------------------------------------
// LDS-free direct-fragment GEMM.  C[M][320] = [A0 | (amsg[b2a]-msg[b2revb])] @ Wt^T
//   Wt[320][BSTRIDE] k-contiguous rows (weight columns), L2-hot (300 KB).
//   Block: 128M x 160N (virtual; no intra-block communication).
//   4 waves 2x2; wave tile 64x80 (4 tm x 5 tn of 16x16x32 MFMA).
//   Fragment load: lane reads 16B at (row = base + l16, k = kt*32 + quad*8).
//   All row strides are 64B-multiples -> each load = 16 aligned 64B lines.
//   K-loop fully imm-offset addressed; depth-2 register prefetch (P/Q sets);
//   NO LDS, NO barriers — compiler emits counted, dependence-driven vmcnt.
//   kt >= KT0 (hidden part): acc += amsg_frag@B + (-msg_frag)@B  (linearity;
//   sign flip via XOR, fp32 accumulate — no intermediate bf16 rounding).
// MODE 0: outp[r*320+col] = relu(acc) bf16
// MODE 2: hid[r*300+col]  = relu(acc + bo[col]) fp32  (col<300)
// ---------------------------------------------------------------------------
template <int KT0, int KT1, int MODE, int BSTRIDE>
__global__ __launch_bounds__(256, 2) void gemm_k(const unsigned short* __restrict__ A0,
                                                 int a0s,
                                                 const unsigned short* __restrict__ amsg,
                                                 const unsigned short* __restrict__ msg,
                                                 const int* __restrict__ b2a,
                                                 const int* __restrict__ b2revb,
                                                 const unsigned short* __restrict__ Wt,
                                                 unsigned short* __restrict__ outp,
                                                 float* __restrict__ hid,
                                                 const float* __restrict__ bo, int M) {
    constexpr int KT = KT0 + KT1;

    const int tid = threadIdx.x;
    const int lane = tid & 63;
    const int wave = tid >> 6;
    const int wm = wave & 1, wn = wave >> 1;
    const int l16 = lane & 15, quad = lane >> 4;

    // ---- XCD-paired m/n decode (bijective incl. tail) ----
    int m0, n0;
    {
        const int bid = blockIdx.x;
        const int MB = (int)(gridDim.x >> 1);
        const int mfull = (MB >> 3) << 3;        // largest mult of 8 <= MB
        const int FULL = mfull << 1;
        int mb, nh;
        if (bid < FULL) {
            nh = (bid >> 3) & 1;
            mb = ((bid >> 4) << 3) + (bid & 7);
        } else {
            const int r = bid - FULL;
            const int rem = MB - mfull;
            nh = (r >= rem) ? 1 : 0;
            mb = mfull + r - nh * rem;
        }
        m0 = mb * 128;
        n0 = nh * 160;
    }

    // ---- per-lane fragment base pointers (loop-invariant; kt via imm) ----
    const unsigned short* pA0[4];
    const unsigned short* pA1[4];
    const unsigned short* pM1[4];
#pragma unroll
    for (int tm = 0; tm < 4; ++tm) {
        const int r = min(m0 + wm * 64 + tm * 16 + l16, M - 1);
        pA0[tm] = A0 + (size_t)r * a0s + quad * 8;
        if constexpr (KT1 > 0) {
            pA1[tm] = amsg + (size_t)b2a[r] * 320 + quad * 8;
            pM1[tm] = msg + (size_t)b2revb[r] * 320 + quad * 8;
        } else {
            pA1[tm] = A0; pM1[tm] = A0;   // unused
        }
    }
    const unsigned short* pB[5];
#pragma unroll
    for (int tn = 0; tn < 5; ++tn)
        pB[tn] = Wt + (size_t)(n0 + wn * 80 + tn * 16 + l16) * BSTRIDE + quad * 8;

    floatx4 acc[4][5];
#pragma unroll
    for (int tm = 0; tm < 4; ++tm)
#pragma unroll
        for (int tn = 0; tn < 5; ++tn) acc[tm][tn] = (floatx4){0.f, 0.f, 0.f, 0.f};

    // ---- depth-2 prefetch sets (all indices compile-time -> registers) ----
    uint4 aP[4], mP[4], bP[5];
    uint4 aQ[4], mQ[4], bQ[5];

    auto ldg = [&](int kt, uint4 (&a)[4], uint4 (&m)[4], uint4 (&b)[5]) {
        if (kt < KT0) {
#pragma unroll
            for (int tm = 0; tm < 4; ++tm)
                a[tm] = *(const uint4*)(pA0[tm] + kt * 32);
        } else {
            const int ko = (kt - KT0) * 32;
#pragma unroll
            for (int tm = 0; tm < 4; ++tm) {
                a[tm] = *(const uint4*)(pA1[tm] + ko);
                m[tm] = *(const uint4*)(pM1[tm] + ko);
            }
        }
#pragma unroll
        for (int tn = 0; tn < 5; ++tn)
            b[tn] = *(const uint4*)(pB[tn] + kt * 32);
    };
    auto mfma_all = [&](const uint4 (&a)[4], const uint4 (&b)[5]) {
#pragma unroll
        for (int tn = 0; tn < 5; ++tn)
#pragma unroll
            for (int tm = 0; tm < 4; ++tm)
                acc[tm][tn] = __builtin_amdgcn_mfma_f32_16x16x32_bf16(
                    __builtin_bit_cast(bf16x8, a[tm]),
                    __builtin_bit_cast(bf16x8, b[tn]), acc[tm][tn], 0, 0, 0);
    };
    auto step = [&](int kt, const uint4 (&a)[4], const uint4 (&m)[4],
                    const uint4 (&b)[5]) {
        mfma_all(a, b);
        if (kt >= KT0) {
            uint4 an[4];
#pragma unroll
            for (int tm = 0; tm < 4; ++tm) an[tm] = negbf8(m[tm]);
            mfma_all(an, b);
        }
    };

    ldg(0, aP, mP, bP);
    if (KT > 1) ldg(1, aQ, mQ, bQ);

#pragma unroll
    for (int kt = 0; kt < KT; ++kt) {
        if ((kt & 1) == 0) {
            step(kt, aP, mP, bP);
            if (kt + 2 < KT) ldg(kt + 2, aP, mP, bP);
        } else {
            step(kt, aQ, mQ, bQ);
            if (kt + 2 < KT) ldg(kt + 2, aQ, mQ, bQ);
        }
    }

    // ---- epilogue ----
    float bias[5];
    if (MODE == 2) {
#pragma unroll
        for (int tn = 0; tn < 5; ++tn) {
            int col = n0 + wn * 80 + tn * 16 + l16;
            bias[tn] = (col < 300) ? bo[col] : 0.f;
        }
    }
#pragma unroll
    for (int tm = 0; tm < 4; ++tm) {
        const int r0 = m0 + wm * 64 + tm * 16 + quad * 4;
#pragma unroll
        for (int tn = 0; tn < 5; ++tn) {
            const int col = n0 + wn * 80 + tn * 16 + l16;
#pragma unroll
            for (int i = 0; i < 4; ++i) {
                int r = r0 + i;
                if (r >= M) continue;
                float c = acc[tm][tn][i];
                if (MODE == 2) {
                    if (col < 300) hid[(size_t)r * 300 + col] = fmaxf(c + bias[tn], 0.f);
                } else {
                    outp[(size_t)r * 320 + col] = f2bf(fmaxf(c, 0.f));
                }
            }
        }
    }
}

// ---------------------------------------------------------------------------
// Per-molecule mean. mol_ids sorted -> binary search row range.
// ---------------------------------------------------------------------------
__global__ __launch_bounds__(320) void mean_k(const float* __restrict__ hid,
                                              const int* __restrict__ mol_ids,
                                              float* __restrict__ out, int nA) {
    int mol = blockIdx.x;
    int lo, hi;
    {
        int l = 0, h = nA;
        while (l < h) { int m = (l + h) >> 1; if (mol_ids[m] < mol) l = m + 1; else h = m; }
        lo = l;
    }
    {
        int l = lo, h = nA;
        while (l < h) { int m = (l + h) >> 1; if (mol_ids[m] < mol + 1) l = m + 1; else h = m; }
        hi = l;
    }
    int col = threadIdx.x;
    if (col >= 300) return;
    float s = 0.f;
    for (int a = lo; a < hi; ++a) s += hid[(size_t)a * 300 + col];
    int cnt = hi - lo;
    out[(size_t)mol * 300 + col] = s / (float)(cnt > 0 ? cnt : 1);
}

// ---------------------------------------------------------------------------
extern "C" void kernel_launch(void* const* d_in, const int* in_sizes, int n_in,
                              void* d_out, int out_size, void* d_ws, size_t ws_size,
                              hipStream_t stream) {
    (void)in_sizes; (void)n_in;
    const float* f_atoms = (const float*)d_in[0];
    const float* f_bonds = (const float*)d_in[1];
    const float* W_i     = (const float*)d_in[2];
    const float* W_h     = (const float*)d_in[3];
    const float* W_o     = (const float*)d_in[4];
    const float* b_o     = (const float*)d_in[5];
    const int*   a2b     = (const int*)d_in[6];
    const int*   b2a     = (const int*)d_in[7];
    const int*   b2revb  = (const int*)d_in[8];
    const int*   mol_ids = (const int*)d_in[9];

    const size_t sz_wih  = 320ull * 480 * 2;
    const size_t sz_wto  = 320ull * 448 * 2;
    const size_t sz_fbp  = 200000ull * 160 * 2;
    const size_t sz_amsg = 100000ull * 320 * 2;
    const size_t sz_msg  = 200000ull * 320 * 2;
    const size_t need = sz_wih + sz_wto + sz_fbp + sz_amsg + 2 * sz_msg;

    if (ws_size < need) {
        dbg_fill<<<(out_size + 255) / 256, 256, 0, stream>>>(
            (float*)d_out, out_size, (float)(ws_size >> 20));
        return;
    }

    char* ws = (char*)d_ws;
    unsigned short* wih  = (unsigned short*)(ws);
    unsigned short* wto  = (unsigned short*)(ws + sz_wih);
    unsigned short* fbp  = (unsigned short*)(ws + sz_wih + sz_wto);
    unsigned short* amsg = (unsigned short*)(ws + sz_wih + sz_wto + sz_fbp);
    unsigned short* msgA = (unsigned short*)(ws + sz_wih + sz_wto + sz_fbp + sz_amsg);
    unsigned short* msgB = (unsigned short*)(ws + sz_wih + sz_wto + sz_fbp + sz_amsg + sz_msg);
    unsigned short* concat = msgA;                     // msgA dead after loop
    float*          hid    = (float*)msgB;             // msgB dead after final gather

    prep_wih<<<600, 256, 0, stream>>>(W_i, W_h, wih);
    prep_wto<<<560, 256, 0, stream>>>(W_o, wto);
    pad_bonds<<<15625, 256, 0, stream>>>(f_bonds, fbp);

    // msgA = relu(f_bonds @ W_i)   (grid = 2*MB, XCD-paired decode inside)
    gemm_k<5, 0, 0, 480><<<dim3(3126), 256, 0, stream>>>(
        fbp, 160, nullptr, nullptr, nullptr, nullptr, wih, msgA, nullptr, nullptr, 200000);

    unsigned short* cur = msgA;
    unsigned short* other = msgB;
    for (int d = 0; d < 3; ++d) {   // DEPTH-1
        gather_sum<40><<<15625, 256, 0, stream>>>(cur, a2b, amsg, 320, 100000);
        gemm_k<5, 10, 0, 480><<<dim3(3126), 256, 0, stream>>>(
            fbp, 160, amsg, cur, b2a, b2revb, wih, other, nullptr, nullptr, 200000);
        unsigned short* t = cur; cur = other; other = t;
    }

    // final gather into concat cols 0..303 (cur == msgB; concat == msgA)
    gather_sum<38><<<14844, 256, 0, stream>>>(cur, a2b, concat, 448, 100000);
    atoms_concat<<<7032, 256, 0, stream>>>(f_atoms, concat);
    // hid = relu(concat @ W_o + b_o)
    gemm_k<14, 0, 2, 448><<<dim3(1564), 256, 0, stream>>>(
        concat, 448, nullptr, nullptr, nullptr, nullptr, wto, nullptr, hid, b_o, 100000);
    mean_k<<<8192, 320, 0, stream>>>(hid, mol_ids, (float*)d_out, 100000);
}

// Round 6
// 1137.842 us; speedup vs baseline: 1.3931x; 1.3931x over previous
//
#include <hip/hip_runtime.h>

// ---------------------------------------------------------------------------
// MPN (chemprop) on MI355X. bf16 MFMA (16x16x32), fp32 accum.
//   relu(inp + m@W_h) == relu([f_bonds | m] @ [W_i ; W_h])  -> no stored inp.
//   combine (a_msg[b2a[b]] - msg[b2revb[b]]) fused into GEMM A-staging.
// R1: 1-D grid, XCD-paired decode (n-half pairs 8 dispatch slots apart).
// R2: de-fused combine — REVERTED (GEMM wasn't staging-bound).
// R3: depth-2 reg prefetch + counted-vmcnt barrier (+8%; MfmaUtil ~15%).
// R4: all-direct fragment loads — REVERTED (16-line fan-out per load; TA
//     transaction-bound, 2x slower). Lesson: global loads must be contiguous.
// R5: split operand paths. A: LDS-staged (coalesced, shared across wn-waves).
//     B: NO LDS — W pre-shuffled to MFMA-fragment-linear layout Wf, one
//     contiguous 1KB coalesced load per (tn,kt) into MFMA operand regs.
//     FAILED: initial GEMM used KT=5 as Wf nb-stride but layout is 15.
// R6: fix — WNB template param decouples Wf layout stride (prep kt-count)
//     from GEMM KT. Initial <5,0,0,15>, loop <5,10,0,15>, final <14,0,2,14>.
// GEMM: block tile 128M x 160N, wave tile 64x80 (4x5), depth-2 P/Q prefetch.
// Workspace (~367 MiB): wih | wto | fbp | amsg | msgA | msgB
// ---------------------------------------------------------------------------

#define DEVFN static __device__ __forceinline__

typedef __attribute__((ext_vector_type(8))) __bf16 bf16x8;
typedef __attribute__((ext_vector_type(4))) float floatx4;

DEVFN unsigned short f2bf(float f) {
    unsigned int u = __float_as_uint(f);
    u += 0x7FFFu + ((u >> 16) & 1u);   // RNE
    return (unsigned short)(u >> 16);
}
DEVFN float bf2f(unsigned int u) { return __uint_as_float(u << 16); }

// packed bf16x2 subtract via fp32 (exact in fp32, RNE back)
DEVFN unsigned int bfsub2(unsigned int a, unsigned int m) {
    float lo = bf2f(a & 0xffffu) - bf2f(m & 0xffffu);
    float hi = bf2f(a >> 16) - bf2f(m >> 16);
    return (unsigned int)f2bf(lo) | ((unsigned int)f2bf(hi) << 16);
}
DEVFN uint4 bfsub8(uint4 a, uint4 m) {
    return make_uint4(bfsub2(a.x, m.x), bfsub2(a.y, m.y),
                      bfsub2(a.z, m.z), bfsub2(a.w, m.w));
}

// ---------------------------------------------------------------------------
__global__ __launch_bounds__(256) void dbg_fill(float* out, int n, float v) {
    int t = blockIdx.x * 256 + threadIdx.x;
    if (t < n) out[t] = v;
}

// W -> fragment-linear layout: Wf[((nb*KTS + kt)*64 + lane)*8 + j]
//   element (n,k): n = nb*16 + (lane&15), k = kt*32 + (lane>>4)*8 + j.
// Wih (KTS=15, K=480): k<147 -> W_i[k][n]; 160<=k<460 -> W_h[k-160][n]; else 0
__global__ __launch_bounds__(256) void prep_wih(const float* __restrict__ Wi,
                                                const float* __restrict__ Wh,
                                                unsigned short* __restrict__ Wt) {
    int t = blockIdx.x * 256 + threadIdx.x;
    if (t >= 320 * 480) return;
    int j = t & 7;
    int lane = (t >> 3) & 63;
    int rest = t >> 9;                 // nb*15 + kt
    int kt = rest % 15, nb = rest / 15;
    int n = nb * 16 + (lane & 15);
    int k = kt * 32 + (lane >> 4) * 8 + j;
    float v = 0.f;
    if (n < 300) {
        if (k < 147) v = Wi[k * 300 + n];
        else if (k >= 160 && k < 460) v = Wh[(k - 160) * 300 + n];
    }
    Wt[t] = f2bf(v);
}

// Wto (KTS=14, K=448): k<300 -> W_o[133+k][n]; 304<=k<437 -> W_o[k-304][n]
__global__ __launch_bounds__(256) void prep_wto(const float* __restrict__ Wo,
                                                unsigned short* __restrict__ Wt) {
    int t = blockIdx.x * 256 + threadIdx.x;
    if (t >= 320 * 448) return;
    int j = t & 7;
    int lane = (t >> 3) & 63;
    int rest = t >> 9;                 // nb*14 + kt
    int kt = rest % 14, nb = rest / 14;
    int n = nb * 16 + (lane & 15);
    int k = kt * 32 + (lane >> 4) * 8 + j;
    float v = 0.f;
    if (n < 300) {
        if (k < 300) v = Wo[(133 + k) * 300 + n];
        else if (k >= 304 && k < 437) v = Wo[(k - 304) * 300 + n];
    }
    Wt[t] = f2bf(v);
}

// f_bonds [200000][147] fp32 -> [200000][160] bf16 padded
__global__ __launch_bounds__(256) void pad_bonds(const float* __restrict__ fb,
                                                 unsigned short* __restrict__ out) {
    int t = blockIdx.x * 256 + threadIdx.x;
    if (t >= 200000 * 20) return;
    int b = t / 20, c = t - b * 20;
    unsigned int o[4];
#pragma unroll
    for (int p = 0; p < 4; ++p) {
        int sc = c * 8 + p * 2;
        float v0 = (sc < 147) ? fb[(size_t)b * 147 + sc] : 0.f;
        float v1 = (sc + 1 < 147) ? fb[(size_t)b * 147 + sc + 1] : 0.f;
        o[p] = (unsigned int)f2bf(v0) | ((unsigned int)f2bf(v1) << 16);
    }
    *(uint4*)(out + (size_t)b * 160 + c * 8) = make_uint4(o[0], o[1], o[2], o[3]);
}

// f_atoms [100000][133] fp32 -> concat cols 304..447
__global__ __launch_bounds__(256) void atoms_concat(const float* __restrict__ fa,
                                                    unsigned short* __restrict__ concat) {
    int t = blockIdx.x * 256 + threadIdx.x;
    if (t >= 100000 * 18) return;
    int a = t / 18, c = t - a * 18;
    unsigned int o[4];
#pragma unroll
    for (int p = 0; p < 4; ++p) {
        int sc = c * 8 + p * 2;
        float v0 = (sc < 133) ? fa[(size_t)a * 133 + sc] : 0.f;
        float v1 = (sc + 1 < 133) ? fa[(size_t)a * 133 + sc + 1] : 0.f;
        o[p] = (unsigned int)f2bf(v0) | ((unsigned int)f2bf(v1) << 16);
    }
    *(uint4*)(concat + (size_t)a * 448 + 304 + c * 8) = make_uint4(o[0], o[1], o[2], o[3]);
}

// a_msg[a] = sum_j msg[a2b[a][j]]
template <int CH>
__global__ __launch_bounds__(256) void gather_sum(const unsigned short* __restrict__ msg,
                                                  const int* __restrict__ a2b,
                                                  unsigned short* __restrict__ out,
                                                  int ostride, int nA) {
    int t = blockIdx.x * 256 + threadIdx.x;
    if (t >= nA * CH) return;
    int a = t / CH, c = t - a * CH;
    float s[8] = {0, 0, 0, 0, 0, 0, 0, 0};
#pragma unroll
    for (int j = 0; j < 6; ++j) {
        int b = a2b[a * 6 + j];
        uint4 v = *(const uint4*)(msg + (size_t)b * 320 + c * 8);
        s[0] += bf2f(v.x & 0xffffu); s[1] += bf2f(v.x >> 16);
        s[2] += bf2f(v.y & 0xffffu); s[3] += bf2f(v.y >> 16);
        s[4] += bf2f(v.z & 0xffffu); s[5] += bf2f(v.z >> 16);
        s[6] += bf2f(v.w & 0xffffu); s[7] += bf2f(v.w >> 16);
    }
    unsigned int o[4];
#pragma unroll
    for (int p = 0; p < 4; ++p)
        o[p] = (unsigned int)f2bf(s[2 * p]) | ((unsigned int)f2bf(s[2 * p + 1]) << 16);
    *(uint4*)(out + (size_t)a * ostride + c * 8) = make_uint4(o[0], o[1], o[2], o[3]);
}

// ---------------------------------------------------------------------------
// Hybrid GEMM.  C[M][320] = [A0 | combine] @ W^T
//   A: LDS-staged per kt (coalesced 32B/row global reads, shared by wn-pair).
//   B: fragment-linear Wf, one contiguous 1KB global load per (tn,kt) straight
//      into MFMA operand regs (no LDS). Wf nb-stride = WNB*512 shorts (WNB =
//      kt-chunk count of the PREP layout, independent of this kernel's KT).
//   Block: 128M x 160N; 4 waves 2x2; wave 64x80 (4 tm x 5 tn).
//   Grid: 1-D, 2*MB blocks, XCD-paired decode.
//   K = (KT0+KT1)*32. kt<KT0: A from A0 (stride a0s). kt>=KT0 (hidden only):
//   A row r = bf16(amsg[b2a[r]] - msg[b2revb[r]]).
//   Depth-2 P/Q register sets; per iter: compute(kt) -> ldg(kt+2) ->
//   stw(kt+1) -> [lgkmcnt(0); s_barrier]  (counted vmcnt rides across).
// MODE 0: outp[r*320+col] = relu(acc) bf16
// MODE 2: hid[r*300+col]  = relu(acc + bo[col]) fp32  (col<300)
// ---------------------------------------------------------------------------
template <int KT0, int KT1, int MODE, int WNB>
__global__ __launch_bounds__(256, 2) void gemm_k(const unsigned short* __restrict__ A0,
                                                 int a0s,
                                                 const unsigned short* __restrict__ amsg,
                                                 const unsigned short* __restrict__ msg,
                                                 const int* __restrict__ b2a,
                                                 const int* __restrict__ b2revb,
                                                 const unsigned short* __restrict__ Wf,
                                                 unsigned short* __restrict__ outp,
                                                 float* __restrict__ hid,
                                                 const float* __restrict__ bo, int M) {
    constexpr int KT = KT0 + KT1;
    __shared__ unsigned short As[2 * 5120];   // [buf][128][40]

    const int tid = threadIdx.x;
    const int lane = tid & 63;
    const int wave = tid >> 6;
    const int wm = wave & 1, wn = wave >> 1;
    const int l16 = lane & 15, quad = lane >> 4;

    // ---- XCD-paired m/n decode (bijective incl. tail) ----
    int m0, n0;
    {
        const int bid = blockIdx.x;
        const int MB = (int)(gridDim.x >> 1);
        const int mfull = (MB >> 3) << 3;        // largest mult of 8 <= MB
        const int FULL = mfull << 1;
        int mb, nh;
        if (bid < FULL) {
            nh = (bid >> 3) & 1;
            mb = ((bid >> 4) << 3) + (bid & 7);
        } else {
            const int r = bid - FULL;
            const int rem = MB - mfull;
            nh = (r >= rem) ? 1 : 0;
            mb = mfull + r - nh * rem;
        }
        m0 = mb * 128;
        n0 = nh * 160;
    }

    // ---- A staging setup (2 threads/row, 32B each) ----
    const int arow = tid >> 1, ahalf = tid & 1;
    const int gr = min(m0 + arow, M - 1);
    const unsigned short* a0p = A0 + (size_t)gr * a0s + ahalf * 16;
    const unsigned short* a1p = nullptr;
    const unsigned short* m1p = nullptr;
    if (KT1 > 0) {
        a1p = amsg + (size_t)b2a[gr] * 320 + ahalf * 16;
        m1p = msg + (size_t)b2revb[gr] * 320 + ahalf * 16;
    }

    // ---- B fragment pointers (fragment-linear Wf; contiguous 1KB/load) ----
    const int nbase = (n0 >> 4) + wn * 5;
    const unsigned short* pB[5];
#pragma unroll
    for (int tn = 0; tn < 5; ++tn)
        pB[tn] = Wf + (size_t)(nbase + tn) * (WNB * 512) + lane * 8;

    // ---- A fragment LDS offsets (shorts) ----
    int aoff[4];
#pragma unroll
    for (int tm = 0; tm < 4; ++tm)
        aoff[tm] = (wm * 64 + tm * 16 + l16) * 40 + quad * 8;

    floatx4 acc[4][5];
#pragma unroll
    for (int tm = 0; tm < 4; ++tm)
#pragma unroll
        for (int tn = 0; tn < 5; ++tn) acc[tm][tn] = (floatx4){0.f, 0.f, 0.f, 0.f};

    // ---- depth-2 register sets: A staging regs + B fragment regs ----
    uint4 aP0, aP1, bP0, bP1, bP2, bP3, bP4;
    uint4 aQ0, aQ1, bQ0, bQ1, bQ2, bQ3, bQ4;

    auto ldg = [&](int kt, uint4& a0r, uint4& a1r,
                   uint4& b0, uint4& b1, uint4& b2, uint4& b3, uint4& b4) {
        if (kt < KT0) {
            a0r = *(const uint4*)(a0p + kt * 32);
            a1r = *(const uint4*)(a0p + kt * 32 + 8);
        } else {
            int ko = (kt - KT0) * 32;
            uint4 va0 = *(const uint4*)(a1p + ko);
            uint4 va1 = *(const uint4*)(a1p + ko + 8);
            uint4 vm0 = *(const uint4*)(m1p + ko);
            uint4 vm1 = *(const uint4*)(m1p + ko + 8);
            a0r = bfsub8(va0, vm0);
            a1r = bfsub8(va1, vm1);
        }
        b0 = *(const uint4*)(pB[0] + kt * 512);
        b1 = *(const uint4*)(pB[1] + kt * 512);
        b2 = *(const uint4*)(pB[2] + kt * 512);
        b3 = *(const uint4*)(pB[3] + kt * 512);
        b4 = *(const uint4*)(pB[4] + kt * 512);
    };
    auto stw = [&](int buf, const uint4& a0r, const uint4& a1r) {
        unsigned short* ab = As + buf * 5120 + arow * 40 + ahalf * 16;
        *(uint4*)(ab) = a0r;
        *(uint4*)(ab + 8) = a1r;
    };
    auto barsync = [&]() {
        asm volatile("s_waitcnt lgkmcnt(0)" ::: "memory");
        __builtin_amdgcn_sched_barrier(0);
        __builtin_amdgcn_s_barrier();
        __builtin_amdgcn_sched_barrier(0);
    };
    auto compute = [&](int buf, const uint4& b0, const uint4& b1,
                       const uint4& b2, const uint4& b3, const uint4& b4) {
        bf16x8 av[4];
#pragma unroll
        for (int tm = 0; tm < 4; ++tm)
            av[tm] = *(const bf16x8*)(As + buf * 5120 + aoff[tm]);
        const bf16x8 bv[5] = {
            __builtin_bit_cast(bf16x8, b0), __builtin_bit_cast(bf16x8, b1),
            __builtin_bit_cast(bf16x8, b2), __builtin_bit_cast(bf16x8, b3),
            __builtin_bit_cast(bf16x8, b4)};
#pragma unroll
        for (int tn = 0; tn < 5; ++tn)
#pragma unroll
            for (int tm = 0; tm < 4; ++tm)
                acc[tm][tn] = __builtin_amdgcn_mfma_f32_16x16x32_bf16(av[tm], bv[tn], acc[tm][tn], 0, 0, 0);
    };

    // ---- prologue: kt0 -> P -> LDS[0]; kt1 -> Q (in flight) ----
    ldg(0, aP0, aP1, bP0, bP1, bP2, bP3, bP4);
    if (KT > 1) ldg(1, aQ0, aQ1, bQ0, bQ1, bQ2, bQ3, bQ4);
    stw(0, aP0, aP1);
    barsync();

#pragma unroll
    for (int kt = 0; kt < KT; ++kt) {
        const int buf = kt & 1;
        if ((kt & 1) == 0) {
            compute(buf, bP0, bP1, bP2, bP3, bP4);
            if (kt + 2 < KT) ldg(kt + 2, aP0, aP1, bP0, bP1, bP2, bP3, bP4);
            if (kt + 1 < KT) { stw(buf ^ 1, aQ0, aQ1); barsync(); }
        } else {
            compute(buf, bQ0, bQ1, bQ2, bQ3, bQ4);
            if (kt + 2 < KT) ldg(kt + 2, aQ0, aQ1, bQ0, bQ1, bQ2, bQ3, bQ4);
            if (kt + 1 < KT) { stw(buf ^ 1, aP0, aP1); barsync(); }
        }
    }

    // ---- epilogue ----
    float bias[5];
    if (MODE == 2) {
#pragma unroll
        for (int tn = 0; tn < 5; ++tn) {
            int col = n0 + wn * 80 + tn * 16 + l16;
            bias[tn] = (col < 300) ? bo[col] : 0.f;
        }
    }
#pragma unroll
    for (int tm = 0; tm < 4; ++tm) {
        const int r0 = m0 + wm * 64 + tm * 16 + quad * 4;
#pragma unroll
        for (int tn = 0; tn < 5; ++tn) {
            const int col = n0 + wn * 80 + tn * 16 + l16;
#pragma unroll
            for (int i = 0; i < 4; ++i) {
                int r = r0 + i;
                if (r >= M) continue;
                float c = acc[tm][tn][i];
                if (MODE == 2) {
                    if (col < 300) hid[(size_t)r * 300 + col] = fmaxf(c + bias[tn], 0.f);
                } else {
                    outp[(size_t)r * 320 + col] = f2bf(fmaxf(c, 0.f));
                }
            }
        }
    }
}

// ---------------------------------------------------------------------------
// Per-molecule mean. mol_ids sorted -> binary search row range.
// ---------------------------------------------------------------------------
__global__ __launch_bounds__(320) void mean_k(const float* __restrict__ hid,
                                              const int* __restrict__ mol_ids,
                                              float* __restrict__ out, int nA) {
    int mol = blockIdx.x;
    int lo, hi;
    {
        int l = 0, h = nA;
        while (l < h) { int m = (l + h) >> 1; if (mol_ids[m] < mol) l = m + 1; else h = m; }
        lo = l;
    }
    {
        int l = lo, h = nA;
        while (l < h) { int m = (l + h) >> 1; if (mol_ids[m] < mol + 1) l = m + 1; else h = m; }
        hi = l;
    }
    int col = threadIdx.x;
    if (col >= 300) return;
    float s = 0.f;
    for (int a = lo; a < hi; ++a) s += hid[(size_t)a * 300 + col];
    int cnt = hi - lo;
    out[(size_t)mol * 300 + col] = s / (float)(cnt > 0 ? cnt : 1);
}

// ---------------------------------------------------------------------------
extern "C" void kernel_launch(void* const* d_in, const int* in_sizes, int n_in,
                              void* d_out, int out_size, void* d_ws, size_t ws_size,
                              hipStream_t stream) {
    (void)in_sizes; (void)n_in;
    const float* f_atoms = (const float*)d_in[0];
    const float* f_bonds = (const float*)d_in[1];
    const float* W_i     = (const float*)d_in[2];
    const float* W_h     = (const float*)d_in[3];
    const float* W_o     = (const float*)d_in[4];
    const float* b_o     = (const float*)d_in[5];
    const int*   a2b     = (const int*)d_in[6];
    const int*   b2a     = (const int*)d_in[7];
    const int*   b2revb  = (const int*)d_in[8];
    const int*   mol_ids = (const int*)d_in[9];

    const size_t sz_wih  = 320ull * 480 * 2;
    const size_t sz_wto  = 320ull * 448 * 2;
    const size_t sz_fbp  = 200000ull * 160 * 2;
    const size_t sz_amsg = 100000ull * 320 * 2;
    const size_t sz_msg  = 200000ull * 320 * 2;
    const size_t need = sz_wih + sz_wto + sz_fbp + sz_amsg + 2 * sz_msg;

    if (ws_size < need) {
        dbg_fill<<<(out_size + 255) / 256, 256, 0, stream>>>(
            (float*)d_out, out_size, (float)(ws_size >> 20));
        return;
    }

    char* ws = (char*)d_ws;
    unsigned short* wih  = (unsigned short*)(ws);
    unsigned short* wto  = (unsigned short*)(ws + sz_wih);
    unsigned short* fbp  = (unsigned short*)(ws + sz_wih + sz_wto);
    unsigned short* amsg = (unsigned short*)(ws + sz_wih + sz_wto + sz_fbp);
    unsigned short* msgA = (unsigned short*)(ws + sz_wih + sz_wto + sz_fbp + sz_amsg);
    unsigned short* msgB = (unsigned short*)(ws + sz_wih + sz_wto + sz_fbp + sz_amsg + sz_msg);
    unsigned short* concat = msgA;                     // msgA dead after loop
    float*          hid    = (float*)msgB;             // msgB dead after final gather

    prep_wih<<<600, 256, 0, stream>>>(W_i, W_h, wih);
    prep_wto<<<560, 256, 0, stream>>>(W_o, wto);
    pad_bonds<<<15625, 256, 0, stream>>>(f_bonds, fbp);

    // msgA = relu(f_bonds @ W_i)   (grid = 2*MB, XCD-paired decode inside)
    gemm_k<5, 0, 0, 15><<<dim3(3126), 256, 0, stream>>>(
        fbp, 160, nullptr, nullptr, nullptr, nullptr, wih, msgA, nullptr, nullptr, 200000);

    unsigned short* cur = msgA;
    unsigned short* other = msgB;
    for (int d = 0; d < 3; ++d) {   // DEPTH-1
        gather_sum<40><<<15625, 256, 0, stream>>>(cur, a2b, amsg, 320, 100000);
        gemm_k<5, 10, 0, 15><<<dim3(3126), 256, 0, stream>>>(
            fbp, 160, amsg, cur, b2a, b2revb, wih, other, nullptr, nullptr, 200000);
        unsigned short* t = cur; cur = other; other = t;
    }

    // final gather into concat cols 0..303 (cur == msgB; concat == msgA)
    gather_sum<38><<<14844, 256, 0, stream>>>(cur, a2b, concat, 448, 100000);
    atoms_concat<<<7032, 256, 0, stream>>>(f_atoms, concat);
    // hid = relu(concat @ W_o + b_o)
    gemm_k<14, 0, 2, 14><<<dim3(1564), 256, 0, stream>>>(
        concat, 448, nullptr, nullptr, nullptr, nullptr, wto, nullptr, hid, b_o, 100000);
    mean_k<<<8192, 320, 0, stream>>>(hid, mol_ids, (float*)d_out, 100000);
}